// Round 14
// baseline (197.602 us; speedup 1.0000x reference)
//
#include <hip/hip_runtime.h>

#define NN 50000
#define NE 100000
#define IN_F 63
#define HID 64
#define NREL 8
#define R1_BLOCKS 2048
#define EPAD (NE + NREL * 63)                 // max padded edges
#define EBLKS ((EPAD + 63) / 64)              // 1571 edge blocks

// ---- degree kernel (proven, ~2us) -----------------------------------------
__global__ __launch_bounds__(256) void deg_kernel(const int* __restrict__ senders,
                                                  const int* __restrict__ receivers,
                                                  float* __restrict__ sdeg,
                                                  float* __restrict__ rdeg) {
    int e = blockIdx.x * 256 + threadIdx.x;
    if (e < NE) {
        atomicAdd(&sdeg[senders[e]], 1.0f);
        atomicAdd(&rdeg[receivers[e]], 1.0f);
    }
}

// ---- K transpose: KT[t][f][i] = K[t][i][f] (32K elems) --------------------
__global__ __launch_bounds__(256) void ktrans_kernel(const float* __restrict__ K,
                                                     float* __restrict__ KT) {
    int idx = blockIdx.x * 256 + threadIdx.x;
    if (idx < NREL * HID * IN_F) {
        int t = idx / (HID * IN_F);
        int rem = idx - t * (HID * IN_F);
        int f = rem / IN_F;
        int i = rem - f * IN_F;
        KT[idx] = K[(size_t)t * IN_F * HID + i * HID + f];
    }
}

// ---- relation bucket sort: block-aggregated reservation, 1 pass -----------
// Segment t occupies [t*NE, t*NE + gcur[t]); order within segment arbitrary.
__global__ __launch_bounds__(256) void rsort_kernel(const int* __restrict__ senders,
                                                    const int* __restrict__ receivers,
                                                    const int* __restrict__ etypes,
                                                    const float* __restrict__ sdeg,
                                                    int* __restrict__ gcur,
                                                    int* __restrict__ sr32,
                                                    float* __restrict__ ns_srt) {
    __shared__ int lcnt[NREL], lloc[NREL];
    if (threadIdx.x < NREL) lcnt[threadIdx.x] = 0;
    __syncthreads();
    const int e = blockIdx.x * 256 + threadIdx.x;
    int t = 0, rank = 0, s = 0, r = 0;
    if (e < NE) {
        t = etypes[e]; s = senders[e]; r = receivers[e];
        rank = atomicAdd(&lcnt[t], 1);
    }
    __syncthreads();
    if (threadIdx.x < NREL)
        lloc[threadIdx.x] = atomicAdd(&gcur[threadIdx.x], lcnt[threadIdx.x]);
    __syncthreads();
    if (e < NE) {
        const int pos = t * NE + lloc[t] + rank;
        sr32[pos] = s | (r << 16);
        ns_srt[pos] = rsqrtf(fmaxf(sdeg[s], 1.0f));
    }
}

// ---- clear pad tails (ns=0 kills dummy edges) -----------------------------
__global__ __launch_bounds__(64) void padclear_kernel(const int* __restrict__ gcur,
                                                      int* __restrict__ sr32,
                                                      float* __restrict__ ns_srt) {
    const int t = blockIdx.x;
    const int c = gcur[t];
    const int end = (c + 63) & ~63;
    const int i = c + threadIdx.x;
    if (i < end) {
        sr32[t * NE + i] = 0;
        ns_srt[t * NE + i] = 0.f;
    }
}

// ---- edge kernel, TRANSPOSED: lane = edge, K wave-uniform -----------------
// r10 evidence: wave-per-edge can't keep 63 broadcast K values in VGPRs
// (VGPR=40, remat, FETCH x2); serial ballot loop exposes gather latency.
// Here: 64-thread block = 64 same-relation edges. Each lane gathers its OWN
// sender row into 64 VGPRs (16 dwordx4 gathers -> 1024 lines in flight).
// K^T rows are wave-uniform scalar loads (constant cache, zero VGPR).
// Outputs go through a bank-swizzled 16KB LDS tile, then 64 coalesced 256B
// atomics. VALU floor ~5us.
__global__ __launch_bounds__(64) void edgeT_kernel(const float* __restrict__ nodes,
                                                   const float* __restrict__ KT,
                                                   const int* __restrict__ sr32,
                                                   const float* __restrict__ ns_srt,
                                                   const int* __restrict__ gcur,
                                                   float* __restrict__ agg) {
    __shared__ float outb[64 * HID];          // 16 KB
    const int lane = threadIdx.x;

    // locate segment: padded segments of roundup64(gcur[t])
    int base = 0, t = -1, local = 0;
#pragma unroll
    for (int tt = 0; tt < NREL; ++tt) {
        const int seg = (gcur[tt] + 63) & ~63;
        if (t < 0 && blockIdx.x * 64 < base + seg) { t = tt; local = blockIdx.x * 64 - base; }
        base += seg;
    }
    if (t < 0) return;

    const int e = t * NE + local + lane;
    const int sr = sr32[e];
    const float nsv = ns_srt[e];
    const int s = sr & 0xFFFF;

    // own sender row -> 64 registers
    float x[HID];
    const float4* x4 = (const float4*)(nodes + (size_t)s * HID);
#pragma unroll
    for (int j = 0; j < 16; ++j) {
        const float4 v = x4[j];
        x[4 * j + 0] = v.x; x[4 * j + 1] = v.y;
        x[4 * j + 2] = v.z; x[4 * j + 3] = v.w;
    }

    const float* KTt = KT + (size_t)t * HID * IN_F;
#pragma unroll 2
    for (int f = 0; f < HID; ++f) {
        const float* kf = KTt + f * IN_F;     // wave-uniform -> s_load
        float a0 = 0.f, a1 = 0.f, a2 = 0.f, a3 = 0.f;
#pragma unroll
        for (int i = 0; i < 60; i += 4) {
            a0 = fmaf(kf[i + 0], x[i + 0], a0);
            a1 = fmaf(kf[i + 1], x[i + 1], a1);
            a2 = fmaf(kf[i + 2], x[i + 2], a2);
            a3 = fmaf(kf[i + 3], x[i + 3], a3);
        }
        a0 = fmaf(kf[60], x[60], a0);
        a1 = fmaf(kf[61], x[61], a1);
        a2 = fmaf(kf[62], x[62], a2);
        outb[lane * HID + ((f + lane) & 63)] = (a0 + a1) + (a2 + a3);  // swizzled
    }
    __syncthreads();

    const int r_l = ((unsigned)sr) >> 16;
    for (int e2 = 0; e2 < 64; ++e2) {
        const float nsu = __shfl(nsv, e2);
        if (nsu == 0.f) continue;             // dummy (uniform)
        const int rr = __shfl(r_l, e2);
        const float val = outb[e2 * HID + ((lane + e2) & 63)];
        atomicAdd(&agg[(size_t)rr * HID + lane], val * nsu);
    }
}

// ---- readout stage 1 (r7 proven) ------------------------------------------
__global__ __launch_bounds__(256) void readout1_kernel(const float* __restrict__ nodes,
                                                       const float* __restrict__ agg,
                                                       const float* __restrict__ rdeg,
                                                       const float* __restrict__ w,
                                                       float* __restrict__ partial) {
    __shared__ float wsum[4];
    const int lane = threadIdx.x & 63;
    const int wid  = threadIdx.x >> 6;
    const int gw = blockIdx.x * 4 + wid;
    const int nw = R1_BLOCKS * 4;
    const float wf = w[lane];

    float local = 0.f;
    for (int n = gw; n < NN; n += nw) {
        float a = agg[(size_t)n * HID + lane];
        float nr = rsqrtf(fmaxf(rdeg[n], 1.0f));
        float root = nodes[(size_t)n * HID + IN_F];   // wave-uniform
        local += fmaxf(a * nr, 0.f) * root;
    }
    float v = local * wf;
#pragma unroll
    for (int o = 32; o > 0; o >>= 1) v += __shfl_xor(v, o, 64);
    if (lane == 0) wsum[wid] = v;
    __syncthreads();
    if (threadIdx.x == 0)
        partial[blockIdx.x] = (wsum[0] + wsum[1]) + (wsum[2] + wsum[3]);
}

// ---- readout stage 2 ------------------------------------------------------
__global__ __launch_bounds__(256) void readout2_kernel(const float* __restrict__ partial,
                                                       const float* __restrict__ b,
                                                       float* __restrict__ out) {
    __shared__ float wsum[4];
    const int lane = threadIdx.x & 63;
    const int wid  = threadIdx.x >> 6;
    float v = 0.f;
    for (int i = threadIdx.x; i < R1_BLOCKS; i += 256) v += partial[i];
#pragma unroll
    for (int o = 32; o > 0; o >>= 1) v += __shfl_xor(v, o, 64);
    if (lane == 0) wsum[wid] = v;
    __syncthreads();
    if (threadIdx.x == 0)
        out[0] = (wsum[0] + wsum[1]) + (wsum[2] + wsum[3]) + b[0];
}

extern "C" void kernel_launch(void* const* d_in, const int* in_sizes, int n_in,
                              void* d_out, int out_size, void* d_ws, size_t ws_size,
                              hipStream_t stream) {
    const float* nodes     = (const float*)d_in[0];
    const int*   senders   = (const int*)d_in[1];
    const int*   receivers = (const int*)d_in[2];
    const int*   etypes    = (const int*)d_in[3];
    // d_in[4] = n_node (single graph; unused)
    const float* kernels   = (const float*)d_in[5];
    const float* dense_w   = (const float*)d_in[6];
    const float* dense_b   = (const float*)d_in[7];
    float* out = (float*)d_out;

    // workspace layout
    float* agg     = (float*)d_ws;                        // NN*HID (12.8MB)
    float* sdeg    = agg + (size_t)NN * HID;              // NN
    float* rdeg    = sdeg + NN;                           // NN
    float* partial = rdeg + NN;                           // R1_BLOCKS
    int*   gcur    = (int*)(partial + R1_BLOCKS);         // NREL
    int*   sr32    = gcur + NREL;                         // NREL*NE (3.2MB)
    float* ns_srt  = (float*)(sr32 + (size_t)NREL * NE);  // NREL*NE (3.2MB)
    float* KT      = ns_srt + (size_t)NREL * NE;          // NREL*HID*IN_F

    // zero: agg + sdeg + rdeg + partial + gcur (contiguous)
    size_t zero_bytes = ((size_t)NN * HID + 2 * NN + R1_BLOCKS) * sizeof(float)
                      + NREL * sizeof(int);
    (void)hipMemsetAsync(d_ws, 0, zero_bytes, stream);

    deg_kernel<<<(NE + 255) / 256, 256, 0, stream>>>(senders, receivers, sdeg, rdeg);
    ktrans_kernel<<<(NREL * HID * IN_F + 255) / 256, 256, 0, stream>>>(kernels, KT);
    rsort_kernel<<<(NE + 255) / 256, 256, 0, stream>>>(senders, receivers, etypes,
                                                       sdeg, gcur, sr32, ns_srt);
    padclear_kernel<<<NREL, 64, 0, stream>>>(gcur, sr32, ns_srt);
    edgeT_kernel<<<EBLKS, 64, 0, stream>>>(nodes, KT, sr32, ns_srt, gcur, agg);

    readout1_kernel<<<R1_BLOCKS, 256, 0, stream>>>(nodes, agg, rdeg, dense_w, partial);
    readout2_kernel<<<1, 256, 0, stream>>>(partial, dense_b, out);
}